// Round 14
// baseline (54.661 us; speedup 1.0000x reference)
//
#include <hip/hip_runtime.h>
#include <hip/hip_bf16.h>

typedef __attribute__((ext_vector_type(8))) short short8;
typedef __attribute__((ext_vector_type(4))) float f32x4;
typedef __attribute__((address_space(1))) const unsigned int glb_u32;
typedef __attribute__((address_space(3))) unsigned int lds_u32;

#define DIMD 128
#define SR 256               // rows per block (4 waves x 64)
#define SC 128               // cols per tile
#define NR 32                // row stripes = 8192/SR
#define NC 64                // col tiles  = 8192/SC

// scale = sqrt(2 * log2(e)) so acc = 2*log2(e)*cos -> exp2(acc) = e^(cos/T);
// logit s = acc * ln2.
#define ZSCALE 1.69864363f
#define LN2 0.6931471805599453f

// ---------------- Kernel 1: normalize rows -> scaled bf16; zero accumulators -
__global__ __launch_bounds__(256) void nrm_kernel(const float* __restrict__ zi,
                                                  const float* __restrict__ zj,
                                                  __hip_bfloat16* __restrict__ zn,
                                                  float* __restrict__ out,
                                                  float* __restrict__ rowsum, int B) {
  if (blockIdx.x == 0 && threadIdx.x == 0) out[0] = 0.0f;
  int wave = threadIdx.x >> 6, lane = threadIdx.x & 63;
  int N = 2 * B;
  int row = blockIdx.x * 4 + wave;
  if (row >= N) return;
  if (lane == 0) rowsum[row] = 0.0f;
  const float* src = (row < B) ? (zi + (size_t)row * DIMD)
                               : (zj + (size_t)(row - B) * DIMD);
  float2 v = *(const float2*)(src + lane * 2);
  float ss = v.x * v.x + v.y * v.y;
  #pragma unroll
  for (int off = 32; off; off >>= 1) ss += __shfl_xor(ss, off);
  float nrm = sqrtf(ss);
  float r = ZSCALE / fmaxf(nrm, 1e-8f);
  __hip_bfloat16* dst = zn + (size_t)row * DIMD + lane * 2;
  dst[0] = __float2bfloat16(v.x * r);
  dst[1] = __float2bfloat16(v.y * r);
}

// ---------------- Kernel 2: zn*zn^T upper-triangle, sum-of-exp --------------
// Mixed-granularity triangle: 256-row stripes x 128-col tiles, tiles (r,c)
// with c >= 2r (1056 tiles). Straddlers (c==2r, 2r+1) mask j>i so every
// unordered pair is computed exactly once; all tiles mirror col-sums into
// rowsum[] (atomicAdd) alongside row-sums. Waves own 64 rows (a[4][4]):
// each 4x ds_read_b128 feeds 16 MFMAs — R10-13's 32-row waves halved this
// ratio and cancelled the symmetry win (FLOP-rate 490->240 TF). Positives
// in tiles c==2r+32 / 2r+33 (both pos[i], pos[i+B] written there).

#define LDB(BB, SUB)                                                          \
  {                                                                           \
    const ushort* lp_ = &lds[((SUB) * 16 + l15) * DIMD];                      \
    _Pragma("unroll")                                                         \
    for (int kc = 0; kc < 4; ++kc) BB[kc] = *(const short8*)(lp_ + roff[kc]); \
  }

#define MM4(ACC, RG, BB)                                                      \
  ACC = __builtin_amdgcn_mfma_f32_16x16x32_bf16(a[RG][0], BB[0], ACC, 0, 0, 0); \
  ACC = __builtin_amdgcn_mfma_f32_16x16x32_bf16(a[RG][1], BB[1], ACC, 0, 0, 0); \
  ACC = __builtin_amdgcn_mfma_f32_16x16x32_bf16(a[RG][2], BB[2], ACC, 0, 0, 0); \
  ACC = __builtin_amdgcn_mfma_f32_16x16x32_bf16(a[RG][3], BB[3], ACC, 0, 0, 0);

#define EPI_PLAIN(ACC, RG, CE, SUB)                                           \
  {                                                                           \
    float e0 = __builtin_amdgcn_exp2f(ACC[0]);                                \
    float e1 = __builtin_amdgcn_exp2f(ACC[1]);                                \
    float e2 = __builtin_amdgcn_exp2f(ACC[2]);                                \
    float e3 = __builtin_amdgcn_exp2f(ACC[3]);                                \
    rs[RG][0] += e0; rs[RG][1] += e1; rs[RG][2] += e2; rs[RG][3] += e3;       \
    CE += (e0 + e1) + (e2 + e3);                                              \
  }

#define EPI_MASK(ACC, RG, CE, SUB)                                            \
  {                                                                           \
    _Pragma("unroll")                                                         \
    for (int rr = 0; rr < 4; ++rr) {                                          \
      int i_ = Rr + (RG) * 16 + lh * 4 + rr;                                  \
      int jg_ = Cc + (SUB) * 16 + l15;                                        \
      float e = (jg_ > i_) ? __builtin_amdgcn_exp2f(ACC[rr]) : 0.0f;          \
      rs[RG][rr] += e; CE += e;                                               \
    }                                                                         \
  }

#define EPI_POS(ACC, RG, CE, SUB)                                             \
  {                                                                           \
    _Pragma("unroll")                                                         \
    for (int rr = 0; rr < 4; ++rr) {                                          \
      int i_ = Rr + (RG) * 16 + lh * 4 + rr;                                  \
      int jg_ = Cc + (SUB) * 16 + l15;                                        \
      float e = __builtin_amdgcn_exp2f(ACC[rr]);                              \
      rs[RG][rr] += e; CE += e;                                               \
      if (jg_ == i_ + B) {                                                    \
        float s_ = ACC[rr] * LN2;                                             \
        pos[i_] = s_; pos[i_ + B] = s_;                                       \
      }                                                                       \
    }                                                                         \
  }

#define CSTORE(CE, SUB)                                                       \
  {                                                                           \
    CE += __shfl_xor(CE, 16);                                                 \
    CE += __shfl_xor(CE, 32);                                                 \
    if (lh == 0) colred[wave][(SUB) * 16 + l15] = CE;                         \
  }

#define SUBSTEP(BCUR, BNXT, SUB, DOPF, EPIM)                                  \
  {                                                                           \
    if (DOPF) { LDB(BNXT, (SUB) + 1) }                                        \
    float ce = 0.0f;                                                          \
    _Pragma("unroll")                                                         \
    for (int rg = 0; rg < 4; ++rg) {                                          \
      f32x4 acc = {0.f, 0.f, 0.f, 0.f};                                       \
      MM4(acc, rg, BCUR)                                                      \
      EPIM(acc, rg, ce, SUB)                                                  \
    }                                                                         \
    CSTORE(ce, SUB)                                                           \
  }

#define RUN8(EPIM)                                                            \
  {                                                                           \
    short8 b0[4], b1[4];                                                      \
    LDB(b0, 0)                                                                \
    SUBSTEP(b0, b1, 0, 1, EPIM)                                               \
    SUBSTEP(b1, b0, 1, 1, EPIM)                                               \
    SUBSTEP(b0, b1, 2, 1, EPIM)                                               \
    SUBSTEP(b1, b0, 3, 1, EPIM)                                               \
    SUBSTEP(b0, b1, 4, 1, EPIM)                                               \
    SUBSTEP(b1, b0, 5, 1, EPIM)                                               \
    SUBSTEP(b0, b1, 6, 1, EPIM)                                               \
    SUBSTEP(b1, b0, 7, 0, EPIM)                                               \
  }

__global__ __launch_bounds__(256) void sim_kernel(const __hip_bfloat16* __restrict__ znb,
                                                  float* __restrict__ rowsum,
                                                  float* __restrict__ pos, int B) {
  const ushort* zn = (const ushort*)znb;
  const int tid = threadIdx.x;
  const int wave = tid >> 6, lane = tid & 63;
  const int l15 = lane & 15, lh = lane >> 4;

  // decode tile (r, c): r in [0,NR), c in [2r, NC)
  int rem = blockIdx.x, r = 0;
  while (rem >= (NC - 2 * r)) { rem -= (NC - 2 * r); ++r; }
  const int c = 2 * r + rem;
  const int d = rem;                    // c - 2r

  const int Rr = r * SR + wave * 64;    // this wave's 64 rows
  const int Cc = c * SC;                // tile's 128 cols

  __shared__ ushort lds[SC * DIMD];     // 32 KB B panel
  __shared__ float colred[4][SC];       // 2 KB col-sum reduce

  // ---- stage B panel (8 global_load_lds, linear dest + pre-swz source) ----
  {
    const int myCol = wave * 4 + lh;
    const int myKb = l15 ^ (myCol & 7);
    const ushort* gsrc0 = zn + (size_t)(Cc + myCol) * DIMD + myKb * 8;
    #pragma unroll
    for (int c_ = 0; c_ < 8; ++c_)
      __builtin_amdgcn_global_load_lds(
          (glb_u32*)(gsrc0 + (size_t)c_ * 16 * DIMD),
          (lds_u32*)&lds[(c_ * 16 + wave * 4) * DIMD], 16, 0, 0);
  }

  // ---- A fragments: 4 row-groups x 4 k-chunks ----
  short8 a[4][4];
  #pragma unroll
  for (int rg = 0; rg < 4; ++rg) {
    const ushort* ar = zn + (size_t)(Rr + rg * 16 + l15) * DIMD + lh * 8;
    #pragma unroll
    for (int kc = 0; kc < 4; ++kc) a[rg][kc] = *(const short8*)(ar + kc * 32);
  }

  float rs[4][4];
  #pragma unroll
  for (int rg = 0; rg < 4; ++rg)
    #pragma unroll
    for (int rr = 0; rr < 4; ++rr) rs[rg][rr] = 0.0f;

  int roff[4];
  #pragma unroll
  for (int kc = 0; kc < 4; ++kc) roff[kc] = ((kc * 4 + lh) ^ (l15 & 7)) * 8;

  __syncthreads();  // drains staging + A loads

  if (d <= 1) {
    RUN8(EPI_MASK)        // diagonal straddlers: strict upper (j > i)
  } else if (d == 32 || d == 33) {
    RUN8(EPI_POS)         // contains the positive diagonal
  } else {
    RUN8(EPI_PLAIN)       // 962 of 1056 tiles: branch-free
  }

  // row-sums: reduce across the 16 lanes sharing (lane>>4), then accumulate
  #pragma unroll
  for (int rg = 0; rg < 4; ++rg) {
    #pragma unroll
    for (int rr = 0; rr < 4; ++rr) {
      #pragma unroll
      for (int off = 1; off < 16; off <<= 1)
        rs[rg][rr] += __shfl_xor(rs[rg][rr], off);
    }
  }
  if (l15 == 0) {
    #pragma unroll
    for (int rg = 0; rg < 4; ++rg)
      #pragma unroll
      for (int rr = 0; rr < 4; ++rr)
        atomicAdd(&rowsum[Rr + rg * 16 + lh * 4 + rr], rs[rg][rr]);
  }

  // mirror: combine 4 waves' col-sums -> rowsum[j] for the tile's 128 cols
  __syncthreads();
  if (tid < SC) {
    float cs = colred[0][tid] + colred[1][tid] + colred[2][tid] + colred[3][tid];
    atomicAdd(&rowsum[Cc + tid], cs);
  }
}

// ---------------- Kernel 3: row_loss = log(sum) - pos; mean over rows -------
__global__ __launch_bounds__(256) void fin_kernel(const float* __restrict__ rowsum,
                                                  const float* __restrict__ pos,
                                                  float* __restrict__ out, int N) {
  int i = blockIdx.x * 256 + threadIdx.x;
  float li = 0.0f;
  if (i < N)
    li = __builtin_amdgcn_logf(rowsum[i]) * LN2 - pos[i];
  #pragma unroll
  for (int off = 32; off; off >>= 1) li += __shfl_xor(li, off);
  __shared__ float red[4];
  int wave = threadIdx.x >> 6, lane = threadIdx.x & 63;
  if (lane == 0) red[wave] = li;
  __syncthreads();
  if (threadIdx.x == 0) {
    float bs = red[0] + red[1] + red[2] + red[3];
    atomicAdd(out, bs / (float)N);
  }
}

extern "C" void kernel_launch(void* const* d_in, const int* in_sizes, int n_in,
                              void* d_out, int out_size, void* d_ws, size_t ws_size,
                              hipStream_t stream) {
  const float* zi = (const float*)d_in[0];
  const float* zj = (const float*)d_in[1];
  const int B = in_sizes[0] / DIMD;   // 4096
  const int N = 2 * B;                // 8192
  float* out = (float*)d_out;

  char* ws = (char*)d_ws;
  __hip_bfloat16* zn = (__hip_bfloat16*)ws;                  // 2 MB
  float* pos = (float*)(ws + (size_t)N * DIMD * 2);          // 32 KB
  float* rowsum = (float*)(ws + (size_t)N * DIMD * 2 + (size_t)N * 4);  // 32 KB

  nrm_kernel<<<N / 4, 256, 0, stream>>>(zi, zj, zn, out, rowsum, B);
  const int ntiles = NR * NC - NR * (NR - 1);   // sum(NC-2r) = 1056
  sim_kernel<<<ntiles, 256, 0, stream>>>(zn, rowsum, pos, B);
  fin_kernel<<<N / 256, 256, 0, stream>>>(rowsum, pos, out, N);
}

// Round 15
// 37.994 us; speedup vs baseline: 1.4387x; 1.4387x over previous
//
#include <hip/hip_runtime.h>
#include <hip/hip_bf16.h>

typedef __attribute__((ext_vector_type(8))) short short8;
typedef __attribute__((ext_vector_type(4))) float f32x4;
typedef __attribute__((address_space(1))) const unsigned int glb_u32;
typedef __attribute__((address_space(3))) unsigned int lds_u32;

#define DIMD 128
#define S 128                // square tile size
#define NS 64                // stripes = 8192 / S
#define NPB 32               // B/S: pos pairs live in tiles c == r + NPB
#define WRW 32               // rows per wave (4 waves x 32 = 128-row stripe)

// scale = sqrt(2 * log2(e)) so acc = 2*log2(e)*cos -> exp2(acc) = e^(cos/T);
// logit s = acc * ln2.
#define ZSCALE 1.69864363f
#define LN2 0.6931471805599453f

// ---------------- Kernel 1: normalize rows -> scaled bf16; zero accumulators -
__global__ __launch_bounds__(256) void nrm_kernel(const float* __restrict__ zi,
                                                  const float* __restrict__ zj,
                                                  __hip_bfloat16* __restrict__ zn,
                                                  float* __restrict__ out,
                                                  float* __restrict__ rowsum, int B) {
  if (blockIdx.x == 0 && threadIdx.x == 0) out[0] = 0.0f;
  int wave = threadIdx.x >> 6, lane = threadIdx.x & 63;
  int N = 2 * B;
  int row = blockIdx.x * 4 + wave;
  if (row >= N) return;
  if (lane == 0) rowsum[row] = 0.0f;
  const float* src = (row < B) ? (zi + (size_t)row * DIMD)
                               : (zj + (size_t)(row - B) * DIMD);
  float2 v = *(const float2*)(src + lane * 2);
  float ss = v.x * v.x + v.y * v.y;
  #pragma unroll
  for (int off = 32; off; off >>= 1) ss += __shfl_xor(ss, off);
  float nrm = sqrtf(ss);
  float r = ZSCALE / fmaxf(nrm, 1e-8f);
  __hip_bfloat16* dst = zn + (size_t)row * DIMD + lane * 2;
  dst[0] = __float2bfloat16(v.x * r);
  dst[1] = __float2bfloat16(v.y * r);
}

// ---------------- Kernel 2: zn*zn^T upper-triangle, sum-of-exp --------------
// 2080 tiles of 128x128 (c>=r), 4 waves x 32 rows. Off-diag tiles add
// row-sums AND mirror col-sums to rowsum[] (atomicAdd). Col-sums are kept in
// cs[8] REGISTERS during the loop (R13's per-sub shfl-reduce chains removed)
// and reduced once at tile end: 8 independent 2-shfl chains -> atomicAdd.
// No colred LDS, no tail barrier; LDS exactly 32 KB -> 5 blocks/CU ceiling.
// Positives only in tiles c==r+NPB; diag tiles (r==c) mask j==i.

#define LDB(BB, SUB)                                                          \
  {                                                                           \
    const ushort* lp_ = &lds[((SUB) * 16 + l15) * DIMD];                      \
    _Pragma("unroll")                                                         \
    for (int kc = 0; kc < 4; ++kc) BB[kc] = *(const short8*)(lp_ + roff[kc]); \
  }

#define MM4(ACC, RG, BB)                                                      \
  ACC = __builtin_amdgcn_mfma_f32_16x16x32_bf16(a[RG][0], BB[0], ACC, 0, 0, 0); \
  ACC = __builtin_amdgcn_mfma_f32_16x16x32_bf16(a[RG][1], BB[1], ACC, 0, 0, 0); \
  ACC = __builtin_amdgcn_mfma_f32_16x16x32_bf16(a[RG][2], BB[2], ACC, 0, 0, 0); \
  ACC = __builtin_amdgcn_mfma_f32_16x16x32_bf16(a[RG][3], BB[3], ACC, 0, 0, 0);

#define EPI(ACC, RG, CE)                                                      \
  {                                                                           \
    float e0 = __builtin_amdgcn_exp2f(ACC[0]);                                \
    float e1 = __builtin_amdgcn_exp2f(ACC[1]);                                \
    float e2 = __builtin_amdgcn_exp2f(ACC[2]);                                \
    float e3 = __builtin_amdgcn_exp2f(ACC[3]);                                \
    rs[RG][0] += e0; rs[RG][1] += e1; rs[RG][2] += e2; rs[RG][3] += e3;       \
    CE += (e0 + e1) + (e2 + e3);                                              \
  }

// one pipelined pair: compute subs S0,S1 from b0,b1; prefetch PF0,PF1
#define PAIR(S0, S1, PF0, PF1, DOPF)                                          \
  {                                                                           \
    f32x4 x0 = {0.f,0.f,0.f,0.f}, x1 = {0.f,0.f,0.f,0.f};                     \
    f32x4 y0 = {0.f,0.f,0.f,0.f}, y1 = {0.f,0.f,0.f,0.f};                     \
    MM4(x0, 0, b0) MM4(x1, 1, b0) MM4(y0, 0, b1) MM4(y1, 1, b1)               \
    if (DOPF) { LDB(b0, PF0) LDB(b1, PF1) }                                   \
    EPI(x0, 0, cs[S0]) EPI(x1, 1, cs[S0])                                     \
    EPI(y0, 0, cs[S1]) EPI(y1, 1, cs[S1])                                     \
  }

__global__ __launch_bounds__(256) void sim_kernel(const __hip_bfloat16* __restrict__ znb,
                                                  float* __restrict__ rowsum,
                                                  float* __restrict__ pos, int B) {
  const ushort* zn = (const ushort*)znb;
  const int tid = threadIdx.x;
  const int wave = tid >> 6, lane = tid & 63;
  const int l15 = lane & 15, lh = lane >> 4;

  // decode upper-triangle tile (r, c), 0 <= r <= c < NS
  int rem = blockIdx.x, r = 0;
  while (rem >= (NS - r)) { rem -= (NS - r); ++r; }
  const int c = r + rem;

  const int Rr = r * S + wave * WRW;   // this wave's 32 rows
  const int Cc = c * S;                // tile's 128 cols

  __shared__ ushort lds[S * DIMD];     // exactly 32 KB B panel

  // ---- stage B panel (8 global_load_lds, linear dest + pre-swz source) ----
  {
    const int myCol = wave * 4 + lh;
    const int myKb = l15 ^ (myCol & 7);
    const ushort* gsrc0 = zn + (size_t)(Cc + myCol) * DIMD + myKb * 8;
    #pragma unroll
    for (int c_ = 0; c_ < 8; ++c_)
      __builtin_amdgcn_global_load_lds(
          (glb_u32*)(gsrc0 + (size_t)c_ * 16 * DIMD),
          (lds_u32*)&lds[(c_ * 16 + wave * 4) * DIMD], 16, 0, 0);
  }

  // ---- A fragments: 2 row-groups x 4 k-chunks ----
  short8 a[2][4];
  #pragma unroll
  for (int rg = 0; rg < 2; ++rg) {
    const ushort* ar = zn + (size_t)(Rr + rg * 16 + l15) * DIMD + lh * 8;
    #pragma unroll
    for (int kc = 0; kc < 4; ++kc) a[rg][kc] = *(const short8*)(ar + kc * 32);
  }

  float rs[2][4];
  #pragma unroll
  for (int rg = 0; rg < 2; ++rg)
    #pragma unroll
    for (int rr = 0; rr < 4; ++rr) rs[rg][rr] = 0.0f;

  float cs[8];
  #pragma unroll
  for (int k = 0; k < 8; ++k) cs[k] = 0.0f;

  int roff[4];
  #pragma unroll
  for (int kc = 0; kc < 4; ++kc) roff[kc] = ((kc * 4 + lh) ^ (l15 & 7)) * 8;

  __syncthreads();  // drains staging + A loads

  if (r == c) {
    // ---- diagonal tile: mask j==i, row-sums only, no mirror ----
    #pragma unroll
    for (int sub = 0; sub < S / 16; ++sub) {
      short8 bb[4];
      LDB(bb, sub)
      #pragma unroll
      for (int rg = 0; rg < 2; ++rg) {
        f32x4 acc = {0.f, 0.f, 0.f, 0.f};
        MM4(acc, rg, bb)
        #pragma unroll
        for (int rr = 0; rr < 4; ++rr) {
          int i_ = Rr + rg * 16 + lh * 4 + rr;   // C/D: row=(lane>>4)*4+reg
          int jg_ = Cc + sub * 16 + l15;         //       col=lane&15
          if (jg_ != i_) rs[rg][rr] += __builtin_amdgcn_exp2f(acc[rr]);
        }
      }
    }
  } else if (c == r + NPB) {
    // ---- pos tile: plain sums + positives on the local diagonal ----
    #pragma unroll
    for (int sub = 0; sub < S / 16; ++sub) {
      short8 bb[4];
      LDB(bb, sub)
      #pragma unroll
      for (int rg = 0; rg < 2; ++rg) {
        f32x4 acc = {0.f, 0.f, 0.f, 0.f};
        MM4(acc, rg, bb)
        #pragma unroll
        for (int rr = 0; rr < 4; ++rr) {
          int i_ = Rr + rg * 16 + lh * 4 + rr;
          int jg_ = Cc + sub * 16 + l15;
          float e = __builtin_amdgcn_exp2f(acc[rr]);
          rs[rg][rr] += e;
          cs[sub] += e;
          if (jg_ == i_ + B) {                   // local diagonal
            float s_ = acc[rr] * LN2;
            pos[i_] = s_;
            pos[i_ + B] = s_;
          }
        }
      }
    }
  } else {
    // ---- plain tile (1984 of 2080): hand-pipelined 2-sub loop ----
    short8 b0[4], b1[4];
    LDB(b0, 0) LDB(b1, 1)
    PAIR(0, 1, 2, 3, 1)
    PAIR(2, 3, 4, 5, 1)
    PAIR(4, 5, 6, 7, 1)
    PAIR(6, 7, 0, 0, 0)
  }

  // row-sums: reduce across the 16 lanes sharing (lane>>4), then accumulate
  #pragma unroll
  for (int rg = 0; rg < 2; ++rg) {
    #pragma unroll
    for (int rr = 0; rr < 4; ++rr) {
      #pragma unroll
      for (int off = 1; off < 16; off <<= 1)
        rs[rg][rr] += __shfl_xor(rs[rg][rr], off);
    }
  }
  if (l15 == 0) {
    #pragma unroll
    for (int rg = 0; rg < 2; ++rg)
      #pragma unroll
      for (int rr = 0; rr < 4; ++rr)
        atomicAdd(&rowsum[Rr + rg * 16 + lh * 4 + rr], rs[rg][rr]);
  }

  // mirror col-sums: 8 independent 2-shfl chains (pipelined), then atomics
  if (r != c) {
    #pragma unroll
    for (int sub = 0; sub < 8; ++sub) {
      float v = cs[sub];
      v += __shfl_xor(v, 16);
      v += __shfl_xor(v, 32);
      if (lh == 0) atomicAdd(&rowsum[Cc + sub * 16 + l15], v);
    }
  }
}

// ---------------- Kernel 3: row_loss = log(sum) - pos; mean over rows -------
__global__ __launch_bounds__(256) void fin_kernel(const float* __restrict__ rowsum,
                                                  const float* __restrict__ pos,
                                                  float* __restrict__ out, int N) {
  int i = blockIdx.x * 256 + threadIdx.x;
  float li = 0.0f;
  if (i < N)
    li = __builtin_amdgcn_logf(rowsum[i]) * LN2 - pos[i];
  #pragma unroll
  for (int off = 32; off; off >>= 1) li += __shfl_xor(li, off);
  __shared__ float red[4];
  int wave = threadIdx.x >> 6, lane = threadIdx.x & 63;
  if (lane == 0) red[wave] = li;
  __syncthreads();
  if (threadIdx.x == 0) {
    float bs = red[0] + red[1] + red[2] + red[3];
    atomicAdd(out, bs / (float)N);
  }
}

extern "C" void kernel_launch(void* const* d_in, const int* in_sizes, int n_in,
                              void* d_out, int out_size, void* d_ws, size_t ws_size,
                              hipStream_t stream) {
  const float* zi = (const float*)d_in[0];
  const float* zj = (const float*)d_in[1];
  const int B = in_sizes[0] / DIMD;   // 4096
  const int N = 2 * B;                // 8192
  float* out = (float*)d_out;

  char* ws = (char*)d_ws;
  __hip_bfloat16* zn = (__hip_bfloat16*)ws;                  // 2 MB
  float* pos = (float*)(ws + (size_t)N * DIMD * 2);          // 32 KB
  float* rowsum = (float*)(ws + (size_t)N * DIMD * 2 + (size_t)N * 4);  // 32 KB

  nrm_kernel<<<N / 4, 256, 0, stream>>>(zi, zj, zn, out, rowsum, B);
  const int ntri = NS * (NS + 1) / 2;   // 2080 upper-tri tiles
  sim_kernel<<<ntri, 256, 0, stream>>>(zn, rowsum, pos, B);
  fin_kernel<<<N / 256, 256, 0, stream>>>(rowsum, pos, out, N);
}